// Round 9
// baseline (936.695 us; speedup 1.0000x reference)
//
#include <hip/hip_runtime.h>
#include <hip/hip_fp16.h>

#define NN 100000
#define NE 1600000
#define IND 64
#define HID 128
#define NCLS 16
#define GEMMB (NN / 16)   // 6250
#define RBLK 50
#define BK 98             // buckets (1024 nodes each)
#define BW 1024           // nodes per bucket
#define EPB 2048          // edges per block in bucket hist/place
#define NBG ((NE + EPB - 1) / EPB)   // 782 blocks per graph

#define AS1VP __attribute__((address_space(1))) void*
#define AS3VP __attribute__((address_space(3))) void*

// ---------------------------------------------------------------------------
// type-pun helpers
__device__ __forceinline__ __half2 as_h2(unsigned u) {
    union { unsigned u; __half2 h; } c; c.u = u; return c.h;
}
__device__ __forceinline__ unsigned as_u32(__half2 h) {
    union { unsigned u; __half2 h; } c; c.h = h; return c.u;
}

// ---------------------------------------------------------------------------
// fp32 -> f16 table conversion (8 elems / thread)
__global__ void conv16_kernel(const float4* __restrict__ x, uint4* __restrict__ o, int n8) {
    int i = blockIdx.x * blockDim.x + threadIdx.x;
    if (i >= n8) return;
    float4 a = x[2 * i], b = x[2 * i + 1];
    uint4 w;
    w.x = as_u32(__floats2half2_rn(a.x, a.y));
    w.y = as_u32(__floats2half2_rn(a.z, a.w));
    w.z = as_u32(__floats2half2_rn(b.x, b.y));
    w.w = as_u32(__floats2half2_rn(b.z, b.w));
    o[i] = w;
}

// ---------------------------------------------------------------------------
// bucket histogram (both graphs)
__global__ void bucket_hist(const int* __restrict__ d0, const int* __restrict__ d1,
                            int* __restrict__ bcnt) {
    __shared__ int h[BK];
    const int bi = blockIdx.x;
    const int g = bi >= NBG;
    const int* dst = g ? d1 : d0;
    const int base = (g ? bi - NBG : bi) * EPB;
    for (int i = threadIdx.x; i < BK; i += 256) h[i] = 0;
    __syncthreads();
    for (int j = 0; j < EPB; j += 256) {
        int e = base + j + threadIdx.x;
        if (e < NE) atomicAdd(&h[dst[e] >> 10], 1);
    }
    __syncthreads();
    for (int i = threadIdx.x; i < BK; i += 256)
        if (h[i]) atomicAdd(&bcnt[g * BK + i], h[i]);
}

// ---------------------------------------------------------------------------
__global__ void bucket_scan(const int* __restrict__ bcnt, int* __restrict__ bbase,
                            int* __restrict__ bcur) {
    int t = threadIdx.x;
    if (t < 2) {
        int run = 0;
        for (int i = 0; i < BK; i++) {
            bbase[t * (BK + 1) + i] = run;
            bcur[t * BK + i] = run;
            run += bcnt[t * BK + i];
        }
        bbase[t * (BK + 1) + BK] = run;
    }
}

// ---------------------------------------------------------------------------
// partition edges into bucket regions: src | (dst&1023)<<17
__global__ void bucket_place(const int* __restrict__ s0, const int* __restrict__ d0,
                             const int* __restrict__ s1, const int* __restrict__ d1,
                             int* __restrict__ bcur,
                             unsigned* __restrict__ p0, unsigned* __restrict__ p1) {
    __shared__ int h[BK], hb[BK];
    const int bi = blockIdx.x;
    const int g = bi >= NBG;
    const int* src = g ? s1 : s0;
    const int* dst = g ? d1 : d0;
    unsigned* pairs = g ? p1 : p0;
    const int base = (g ? bi - NBG : bi) * EPB;
    for (int i = threadIdx.x; i < BK; i += 256) h[i] = 0;
    __syncthreads();
    for (int j = 0; j < EPB; j += 256) {
        int e = base + j + threadIdx.x;
        if (e < NE) atomicAdd(&h[dst[e] >> 10], 1);
    }
    __syncthreads();
    for (int i = threadIdx.x; i < BK; i += 256) {
        hb[i] = h[i] ? atomicAdd(&bcur[g * BK + i], h[i]) : 0;
        h[i] = 0;
    }
    __syncthreads();
    for (int j = 0; j < EPB; j += 256) {
        int e = base + j + threadIdx.x;
        if (e < NE) {
            int d = dst[e];
            int b = d >> 10;
            int slot = atomicAdd(&h[b], 1);
            pairs[hb[b] + slot] = (unsigned)src[e] | ((unsigned)(d & 1023) << 17);
        }
    }
}

// ---------------------------------------------------------------------------
// one block per bucket: LDS hist + scan, write rowend + ssrc
__global__ __launch_bounds__(256) void bucket_final(
    const unsigned* __restrict__ p0, const unsigned* __restrict__ p1,
    const int* __restrict__ bbase,
    int* __restrict__ row0, int* __restrict__ row1,
    int* __restrict__ ss0, int* __restrict__ ss1) {
    __shared__ int cnt[BW];
    __shared__ int ex[BW];
    __shared__ int aux[256];
    const int bi = blockIdx.x;
    const int g = bi >= BK;
    const int b = g ? bi - BK : bi;
    const unsigned* pairs = g ? p1 : p0;
    int* rowend = g ? row1 : row0;
    int* ssrc = g ? ss1 : ss0;
    const int ebase = bbase[g * (BK + 1) + b];
    const int eend = bbase[g * (BK + 1) + b + 1];
    const int tid = threadIdx.x;

    for (int i = tid; i < BW; i += 256) cnt[i] = 0;
    __syncthreads();
    for (int e = ebase + tid; e < eend; e += 256)
        atomicAdd(&cnt[pairs[e] >> 17], 1);
    __syncthreads();

    int c0 = cnt[4 * tid], c1 = cnt[4 * tid + 1], c2 = cnt[4 * tid + 2], c3 = cnt[4 * tid + 3];
    aux[tid] = c0 + c1 + c2 + c3;
    __syncthreads();
    for (int off = 1; off < 256; off <<= 1) {
        int v = (tid >= off) ? aux[tid - off] : 0;
        __syncthreads();
        aux[tid] += v;
        __syncthreads();
    }
    int excl = tid ? aux[tid - 1] : 0;
    ex[4 * tid] = excl;
    ex[4 * tid + 1] = excl + c0;
    ex[4 * tid + 2] = excl + c0 + c1;
    ex[4 * tid + 3] = excl + c0 + c1 + c2;

    const int nodebase = b * BW + 4 * tid;
    if (nodebase + 0 < NN) rowend[nodebase + 0] = ebase + excl + c0;
    if (nodebase + 1 < NN) rowend[nodebase + 1] = ebase + excl + c0 + c1;
    if (nodebase + 2 < NN) rowend[nodebase + 2] = ebase + excl + c0 + c1 + c2;
    if (nodebase + 3 < NN) rowend[nodebase + 3] = ebase + excl + c0 + c1 + c2 + c3;
    __syncthreads();

    for (int e = ebase + tid; e < eend; e += 256) {
        unsigned pk = pairs[e];
        int dl = pk >> 17;
        int pos = ebase + atomicAdd(&ex[dl], 1);
        ssrc[pos] = (int)(pk & 0x1FFFFu);
    }
}

// ---------------------------------------------------------------------------
__device__ __forceinline__ void hacc4(__half2* hacc, uint4 v) {
    hacc[0] = __hadd2(hacc[0], as_h2(v.x));
    hacc[1] = __hadd2(hacc[1], as_h2(v.y));
    hacc[2] = __hadd2(hacc[2], as_h2(v.z));
    hacc[3] = __hadd2(hacc[3], as_h2(v.w));
}

// ---------------------------------------------------------------------------
// Fused SAGE layer. Gather rows via async global_load_lds (direct-to-LDS DMA,
// no VGPR return path — the register allocator cannot serialize it). Each
// wave issues 8 row-loads back-to-back into its private 8-slot stage buffer,
// waits vmcnt(0) once, accumulates from LDS with v_pk_add_f16.
template<int KS, bool REDUCE>
__global__ __launch_bounds__(256) void sage_fused(
    const float* __restrict__ xf, const uint4* __restrict__ x16,
    const int* __restrict__ ssrc, const int* __restrict__ rowend,
    const float* __restrict__ Ws, const float* __restrict__ Wn,
    float* __restrict__ outR, unsigned* __restrict__ outH) {
    __shared__ float xms[16][2 * KS + 4];
    __shared__ float part[4][128];
    __shared__ unsigned stage[4 * 8 * 256];   // 4 waves x 8 slots x 1 KB

    const int tid = threadIdx.x;
    const int n0 = blockIdx.x * 16;
    const int RW = KS / 8;  // uint4 per f16 row
    const unsigned* xu = (const unsigned*)x16;

    // ---- self staging ----
    {
        int node = tid / 16, c = tid % 16;
        if constexpr (KS == IND) {
            float4 v = ((const float4*)xf)[(size_t)(n0 + node) * 16 + c];
            *(float4*)&xms[node][c * 4] = v;
        } else {
            uint4 u = x16[(size_t)(n0 + node) * RW + c];
            float2 f0 = __half22float2(as_h2(u.x));
            float2 f1 = __half22float2(as_h2(u.y));
            float2 f2 = __half22float2(as_h2(u.z));
            float2 f3 = __half22float2(as_h2(u.w));
            *(float4*)&xms[node][c * 8] = make_float4(f0.x, f0.y, f1.x, f1.y);
            *(float4*)&xms[node][c * 8 + 4] = make_float4(f2.x, f2.y, f3.x, f3.y);
        }
    }

    // ---- neighbor mean aggregation via async DMA gather ----
    {
        const int nb = tid >> 4;            // node 0..15
        const int n = n0 + nb;
        const int start = (n == 0) ? 0 : rowend[n - 1];
        const int end = rowend[n];
        const int deg = end - start;
        const int liw = tid & 63;           // lane in wave
        unsigned* wstage = stage + (tid >> 6) * (8 * 256);
        __half2 hacc[4];
#pragma unroll
        for (int j = 0; j < 4; j++) hacc[j] = __float2half2_rn(0.0f);

        if constexpr (KS == HID) {
            // 16 lanes/node (full 256 B row), 4 nodes/wave; slot = 4 rows.
            const int l = tid & 15;
            int m = deg;
            m = max(m, __shfl_xor(m, 16));
            m = max(m, __shfl_xor(m, 32));
            const int groups = (m + 7) >> 3;
            for (int gg = 0; gg < groups; gg++) {
#pragma unroll
                for (int s = 0; s < 8; s++) {
                    int e = start + gg * 8 + s;
                    e = min(e, end - 1);
                    e = max(e, 0);
                    int srcn = ssrc[e];
                    const unsigned* gp = xu + (size_t)srcn * 64 + l * 4;
                    __builtin_amdgcn_global_load_lds((AS1VP)(void*)gp,
                                                     (AS3VP)(void*)(wstage + s * 256),
                                                     16, 0, 0);
                }
                __builtin_amdgcn_s_waitcnt(0x0F70);  // vmcnt(0)
#pragma unroll
                for (int s = 0; s < 8; s++) {
                    if (gg * 8 + s < deg) {
                        uint4 v = *(const uint4*)(wstage + s * 256 + liw * 4);
                        hacc4(hacc, v);
                    }
                }
            }
            float iv = 1.0f / fmaxf((float)deg, 1.0f);
            float2 f0 = __half22float2(hacc[0]);
            float2 f1 = __half22float2(hacc[1]);
            float2 f2 = __half22float2(hacc[2]);
            float2 f3 = __half22float2(hacc[3]);
            *(float4*)&xms[nb][KS + l * 8] =
                make_float4(f0.x * iv, f0.y * iv, f1.x * iv, f1.y * iv);
            *(float4*)&xms[nb][KS + l * 8 + 4] =
                make_float4(f2.x * iv, f2.y * iv, f3.x * iv, f3.y * iv);
        } else {
            // 8 lanes/node x 2 chains (even/odd edges), 128 B rows;
            // slot = 4 nodes x 2 chains x 128 B.
            const int sub = tid & 15;
            const int l = sub & 7;
            const int h = sub >> 3;
            const int cdeg = (deg + 1 - h) >> 1;   // edges in this chain
            int m = cdeg;
            m = max(m, __shfl_xor(m, 8));
            m = max(m, __shfl_xor(m, 16));
            m = max(m, __shfl_xor(m, 32));
            const int groups = (m + 7) >> 3;
            for (int gg = 0; gg < groups; gg++) {
#pragma unroll
                for (int s = 0; s < 8; s++) {
                    int e = start + ((gg * 8 + s) << 1) + h;
                    e = min(e, end - 1);
                    e = max(e, 0);
                    int srcn = ssrc[e];
                    const unsigned* gp = xu + (size_t)srcn * 32 + l * 4;
                    __builtin_amdgcn_global_load_lds((AS1VP)(void*)gp,
                                                     (AS3VP)(void*)(wstage + s * 256),
                                                     16, 0, 0);
                }
                __builtin_amdgcn_s_waitcnt(0x0F70);  // vmcnt(0)
#pragma unroll
                for (int s = 0; s < 8; s++) {
                    if (gg * 8 + s < cdeg) {
                        uint4 v = *(const uint4*)(wstage + s * 256 + liw * 4);
                        hacc4(hacc, v);
                    }
                }
            }
#pragma unroll
            for (int j = 0; j < 4; j++) {
                int t = __shfl_xor((int)as_u32(hacc[j]), 8);
                hacc[j] = __hadd2(hacc[j], as_h2((unsigned)t));
            }
            if (h == 0) {
                float iv = 1.0f / fmaxf((float)deg, 1.0f);
                float2 f0 = __half22float2(hacc[0]);
                float2 f1 = __half22float2(hacc[1]);
                float2 f2 = __half22float2(hacc[2]);
                float2 f3 = __half22float2(hacc[3]);
                *(float4*)&xms[nb][KS + l * 8] =
                    make_float4(f0.x * iv, f0.y * iv, f1.x * iv, f1.y * iv);
                *(float4*)&xms[nb][KS + l * 8 + 4] =
                    make_float4(f2.x * iv, f2.y * iv, f3.x * iv, f3.y * iv);
            }
        }
    }
    __syncthreads();

    // ---- GEMM: out = relu([xs|ms] @ [Ws;Wn]) ----
    const int p = tid % 64;
    const int q = tid / 64;
    float a00 = 0, a01 = 0, a10 = 0, a11 = 0, a20 = 0, a21 = 0, a30 = 0, a31 = 0;

#pragma unroll
    for (int seg = 0; seg < 2; seg++) {
        const float* __restrict__ W = seg ? Wn : Ws;
        const int koff = seg * KS;
#pragma unroll 2
        for (int k = 0; k < KS; k += 4) {
            const float* Wk = W + (size_t)k * HID + 2 * p;
            float2 w0 = *(const float2*)(Wk);
            float2 w1 = *(const float2*)(Wk + HID);
            float2 w2 = *(const float2*)(Wk + 2 * HID);
            float2 w3 = *(const float2*)(Wk + 3 * HID);
            float4 v0 = *(const float4*)&xms[4 * q + 0][koff + k];
            float4 v1 = *(const float4*)&xms[4 * q + 1][koff + k];
            float4 v2 = *(const float4*)&xms[4 * q + 2][koff + k];
            float4 v3 = *(const float4*)&xms[4 * q + 3][koff + k];
            a00 += v0.x * w0.x + v0.y * w1.x + v0.z * w2.x + v0.w * w3.x;
            a01 += v0.x * w0.y + v0.y * w1.y + v0.z * w2.y + v0.w * w3.y;
            a10 += v1.x * w0.x + v1.y * w1.x + v1.z * w2.x + v1.w * w3.x;
            a11 += v1.x * w0.y + v1.y * w1.y + v1.z * w2.y + v1.w * w3.y;
            a20 += v2.x * w0.x + v2.y * w1.x + v2.z * w2.x + v2.w * w3.x;
            a21 += v2.x * w0.y + v2.y * w1.y + v2.z * w2.y + v2.w * w3.y;
            a30 += v3.x * w0.x + v3.y * w1.x + v3.z * w2.x + v3.w * w3.x;
            a31 += v3.x * w0.y + v3.y * w1.y + v3.z * w2.y + v3.w * w3.y;
        }
    }

    if constexpr (!REDUCE) {
        float r0, r1;
        r0 = fmaxf(a00, 0.f); r1 = fmaxf(a01, 0.f);
        outH[(size_t)(n0 + 4 * q + 0) * 64 + p] = as_u32(__floats2half2_rn(r0, r1));
        r0 = fmaxf(a10, 0.f); r1 = fmaxf(a11, 0.f);
        outH[(size_t)(n0 + 4 * q + 1) * 64 + p] = as_u32(__floats2half2_rn(r0, r1));
        r0 = fmaxf(a20, 0.f); r1 = fmaxf(a21, 0.f);
        outH[(size_t)(n0 + 4 * q + 2) * 64 + p] = as_u32(__floats2half2_rn(r0, r1));
        r0 = fmaxf(a30, 0.f); r1 = fmaxf(a31, 0.f);
        outH[(size_t)(n0 + 4 * q + 3) * 64 + p] = as_u32(__floats2half2_rn(r0, r1));
    } else {
        float s0 = fmaxf(a00, 0.f) + fmaxf(a10, 0.f) + fmaxf(a20, 0.f) + fmaxf(a30, 0.f);
        float s1 = fmaxf(a01, 0.f) + fmaxf(a11, 0.f) + fmaxf(a21, 0.f) + fmaxf(a31, 0.f);
        *(float2*)&part[q][2 * p] = make_float2(s0, s1);
        __syncthreads();
        if (tid < 128) {
            float s = part[0][tid] + part[1][tid] + part[2][tid] + part[3][tid];
            outR[(size_t)blockIdx.x * 128 + tid] = s;
        }
    }
}

// ---------------------------------------------------------------------------
__global__ void reduce1_kernel(const float* __restrict__ p0, const float* __restrict__ p1,
                               float* __restrict__ p2) {
    const int bb = blockIdx.x;
    const int tid = threadIdx.x;
    const int g = tid >> 7;
    const int col = tid & 127;
    const float* p = g ? p1 : p0;
    const int per = GEMMB / RBLK;
    float s = 0.0f;
    for (int r = 0; r < per; r++) s += p[(size_t)(bb * per + r) * 128 + col];
    p2[(size_t)bb * 256 + tid] = s;
}

__global__ void final_kernel(const float* __restrict__ p2,
                             const float* __restrict__ Wlin1,
                             const float* __restrict__ Wlin2,
                             float* __restrict__ out) {
    __shared__ float rep[2][HID];
    __shared__ float sg[32];
    const int tid = threadIdx.x;
    float s = 0.0f;
    for (int r = 0; r < RBLK; r++) s += p2[r * 256 + tid];
    rep[tid >> 7][tid & 127] = s * (1.0f / (float)NN);
    __syncthreads();
    if (tid < 32) {
        const int g = tid / 16;
        const int c = tid % 16;
        const float* W = g ? Wlin2 : Wlin1;
        float a = 0.0f;
        for (int k = 0; k < HID; k++) a += rep[g][k] * W[k * NCLS + c];
        sg[tid] = 1.0f / (1.0f + expf(-a));
    }
    __syncthreads();
    if (tid < 16) out[tid] = 0.5f * (sg[tid] + sg[16 + tid]);
}

// ---------------------------------------------------------------------------
extern "C" void kernel_launch(void* const* d_in, const int* in_sizes, int n_in,
                              void* d_out, int out_size, void* d_ws, size_t ws_size,
                              hipStream_t stream) {
    const float* feats = (const float*)d_in[0];
    const int* srcp[2] = {(const int*)d_in[1], (const int*)d_in[3]};
    const int* dstp[2] = {(const int*)d_in[2], (const int*)d_in[4]};
    const float* Ws1[2] = {(const float*)d_in[5], (const float*)d_in[10]};
    const float* Wn1[2] = {(const float*)d_in[6], (const float*)d_in[11]};
    const float* Ws2[2] = {(const float*)d_in[7], (const float*)d_in[12]};
    const float* Wn2[2] = {(const float*)d_in[8], (const float*)d_in[13]};
    const float* Wlin[2] = {(const float*)d_in[9], (const float*)d_in[14]};

    // workspace layout (~90 MB), 16B-aligned sections
    char* w = (char*)d_ws;
    uint4* fb16 = (uint4*)w;        w += (size_t)NN * IND * 2;      // feats f16
    uint4* h1h = (uint4*)w;         w += (size_t)NN * HID * 2;      // h1 f16
    float* part0 = (float*)w;       w += (size_t)GEMMB * 128 * 4;
    float* part1 = (float*)w;       w += (size_t)GEMMB * 128 * 4;
    float* p2 = (float*)w;          w += (size_t)RBLK * 256 * 4;
    unsigned* pr0 = (unsigned*)w;   w += (size_t)NE * 4;
    unsigned* pr1 = (unsigned*)w;   w += (size_t)NE * 4;
    int* ss0 = (int*)w;             w += (size_t)NE * 4;
    int* ss1 = (int*)w;             w += (size_t)NE * 4;
    int* row0 = (int*)w;            w += (size_t)NN * 4;
    int* row1 = (int*)w;            w += (size_t)NN * 4;
    int* bcnt = (int*)w;            w += 2 * BK * 4;
    int* bbase = (int*)w;           w += 2 * (BK + 1) * 4;
    int* bcur = (int*)w;            w += 2 * BK * 4;

    // feats -> f16 table
    conv16_kernel<<<(NN * IND / 8 + 255) / 256, 256, 0, stream>>>(
        (const float4*)feats, fb16, NN * IND / 8);

    // bucketed CSR build, both graphs
    (void)hipMemsetAsync(bcnt, 0, 2 * BK * 4, stream);
    bucket_hist<<<2 * NBG, 256, 0, stream>>>(dstp[0], dstp[1], bcnt);
    bucket_scan<<<1, 64, 0, stream>>>(bcnt, bbase, bcur);
    bucket_place<<<2 * NBG, 256, 0, stream>>>(srcp[0], dstp[0], srcp[1], dstp[1],
                                              bcur, pr0, pr1);
    bucket_final<<<2 * BK, 256, 0, stream>>>(pr0, pr1, bbase, row0, row1, ss0, ss1);

    const int* ssg[2] = {ss0, ss1};
    const int* rowg[2] = {row0, row1};
    float* partG[2] = {part0, part1};

    for (int g = 0; g < 2; g++) {
        sage_fused<IND, false><<<GEMMB, 256, 0, stream>>>(
            feats, fb16, ssg[g], rowg[g], Ws1[g], Wn1[g], nullptr, (unsigned*)h1h);
        sage_fused<HID, true><<<GEMMB, 256, 0, stream>>>(
            nullptr, h1h, ssg[g], rowg[g], Ws2[g], Wn2[g], partG[g], nullptr);
    }

    reduce1_kernel<<<RBLK, 256, 0, stream>>>(part0, part1, p2);
    final_kernel<<<1, 256, 0, stream>>>(p2, Wlin[0], Wlin[1], (float*)d_out);
}

// Round 10
// 841.058 us; speedup vs baseline: 1.1137x; 1.1137x over previous
//
#include <hip/hip_runtime.h>
#include <hip/hip_fp16.h>

#define NN 100000
#define NE 1600000
#define IND 64
#define HID 128
#define NCLS 16
#define GEMMB (NN / 16)   // 6250 blocks per graph
#define RBLK 50
#define BK 98             // buckets (1024 nodes each)
#define BW 1024           // nodes per bucket
#define EPB 2048          // edges per block in bucket hist/place
#define NBG ((NE + EPB - 1) / EPB)   // 782 blocks per graph

typedef float v2f __attribute__((ext_vector_type(2)));

// ---------------------------------------------------------------------------
// fp8 e4m3 helpers (HW cvt on gfx950; template HI so builtin sees a constant)
__device__ __forceinline__ float fp8_sw_unpack(unsigned b) {
    unsigned s = (b >> 7) & 1u, em = b & 0x7fu;
    return __uint_as_float((s << 31) | (em << 20)) * 0x1p+120f;
}
__device__ __forceinline__ unsigned fp8_sw_pack(float f) {
    float c = fminf(fmaxf(f, -448.f), 448.f) * 0x1p-120f;
    unsigned b = __float_as_uint(c);
    unsigned s = b >> 31; b &= 0x7fffffffu;
    b = b + 0x7ffffu + ((b >> 20) & 1u);
    unsigned em = b >> 20;
    if (em > 0x7eu) em = 0x7eu;
    return (s << 7) | em;
}
template<bool HI>
__device__ __forceinline__ unsigned pk8(float a, float b, unsigned old) {
#if __has_builtin(__builtin_amdgcn_cvt_pk_fp8_f32)
    return (unsigned)__builtin_amdgcn_cvt_pk_fp8_f32(a, b, (int)old, HI);
#else
    unsigned v = fp8_sw_pack(a) | (fp8_sw_pack(b) << 8);
    return HI ? ((old & 0x0000ffffu) | (v << 16)) : ((old & 0xffff0000u) | v);
#endif
}
template<bool HI>
__device__ __forceinline__ v2f upk8(unsigned u) {
#if __has_builtin(__builtin_amdgcn_cvt_pk_f32_fp8)
    return __builtin_amdgcn_cvt_pk_f32_fp8((int)u, HI);
#else
    unsigned x = HI ? (u >> 16) : u;
    v2f r; r.x = fp8_sw_unpack(x & 0xffu); r.y = fp8_sw_unpack((x >> 8) & 0xffu);
    return r;
#endif
}

__device__ __forceinline__ void bacc16(float* a, uint4 v) {
    v2f t;
    t = upk8<false>(v.x); a[0] += t.x;  a[1] += t.y;
    t = upk8<true>(v.x);  a[2] += t.x;  a[3] += t.y;
    t = upk8<false>(v.y); a[4] += t.x;  a[5] += t.y;
    t = upk8<true>(v.y);  a[6] += t.x;  a[7] += t.y;
    t = upk8<false>(v.z); a[8] += t.x;  a[9] += t.y;
    t = upk8<true>(v.z);  a[10] += t.x; a[11] += t.y;
    t = upk8<false>(v.w); a[12] += t.x; a[13] += t.y;
    t = upk8<true>(v.w);  a[14] += t.x; a[15] += t.y;
}

// ---------------------------------------------------------------------------
// feats fp32 -> fp8 table (4 elems / thread)
__global__ void conv8_kernel(const float4* __restrict__ x, unsigned* __restrict__ o, int n4) {
    int i = blockIdx.x * blockDim.x + threadIdx.x;
    if (i >= n4) return;
    float4 v = x[i];
    unsigned w = pk8<false>(v.x, v.y, 0u);
    w = pk8<true>(v.z, v.w, w);
    o[i] = w;
}

// ---------------------------------------------------------------------------
// bucket histogram (both graphs)
__global__ void bucket_hist(const int* __restrict__ d0, const int* __restrict__ d1,
                            int* __restrict__ bcnt) {
    __shared__ int h[BK];
    const int bi = blockIdx.x;
    const int g = bi >= NBG;
    const int* dst = g ? d1 : d0;
    const int base = (g ? bi - NBG : bi) * EPB;
    for (int i = threadIdx.x; i < BK; i += 256) h[i] = 0;
    __syncthreads();
    for (int j = 0; j < EPB; j += 256) {
        int e = base + j + threadIdx.x;
        if (e < NE) atomicAdd(&h[dst[e] >> 10], 1);
    }
    __syncthreads();
    for (int i = threadIdx.x; i < BK; i += 256)
        if (h[i]) atomicAdd(&bcnt[g * BK + i], h[i]);
}

// ---------------------------------------------------------------------------
__global__ void bucket_scan(const int* __restrict__ bcnt, int* __restrict__ bbase,
                            int* __restrict__ bcur) {
    int t = threadIdx.x;
    if (t < 2) {
        int run = 0;
        for (int i = 0; i < BK; i++) {
            bbase[t * (BK + 1) + i] = run;
            bcur[t * BK + i] = run;
            run += bcnt[t * BK + i];
        }
        bbase[t * (BK + 1) + BK] = run;
    }
}

// ---------------------------------------------------------------------------
// partition edges into bucket regions: src | (dst&1023)<<17
__global__ void bucket_place(const int* __restrict__ s0, const int* __restrict__ d0,
                             const int* __restrict__ s1, const int* __restrict__ d1,
                             int* __restrict__ bcur,
                             unsigned* __restrict__ p0, unsigned* __restrict__ p1) {
    __shared__ int h[BK], hb[BK];
    const int bi = blockIdx.x;
    const int g = bi >= NBG;
    const int* src = g ? s1 : s0;
    const int* dst = g ? d1 : d0;
    unsigned* pairs = g ? p1 : p0;
    const int base = (g ? bi - NBG : bi) * EPB;
    for (int i = threadIdx.x; i < BK; i += 256) h[i] = 0;
    __syncthreads();
    for (int j = 0; j < EPB; j += 256) {
        int e = base + j + threadIdx.x;
        if (e < NE) atomicAdd(&h[dst[e] >> 10], 1);
    }
    __syncthreads();
    for (int i = threadIdx.x; i < BK; i += 256) {
        hb[i] = h[i] ? atomicAdd(&bcur[g * BK + i], h[i]) : 0;
        h[i] = 0;
    }
    __syncthreads();
    for (int j = 0; j < EPB; j += 256) {
        int e = base + j + threadIdx.x;
        if (e < NE) {
            int d = dst[e];
            int b = d >> 10;
            int slot = atomicAdd(&h[b], 1);
            pairs[hb[b] + slot] = (unsigned)src[e] | ((unsigned)(d & 1023) << 17);
        }
    }
}

// ---------------------------------------------------------------------------
// one block per bucket: LDS hist + scan, write rowend + ssrc
__global__ __launch_bounds__(256) void bucket_final(
    const unsigned* __restrict__ p0, const unsigned* __restrict__ p1,
    const int* __restrict__ bbase,
    int* __restrict__ row0, int* __restrict__ row1,
    int* __restrict__ ss0, int* __restrict__ ss1) {
    __shared__ int cnt[BW];
    __shared__ int ex[BW];
    __shared__ int aux[256];
    const int bi = blockIdx.x;
    const int g = bi >= BK;
    const int b = g ? bi - BK : bi;
    const unsigned* pairs = g ? p1 : p0;
    int* rowend = g ? row1 : row0;
    int* ssrc = g ? ss1 : ss0;
    const int ebase = bbase[g * (BK + 1) + b];
    const int eend = bbase[g * (BK + 1) + b + 1];
    const int tid = threadIdx.x;

    for (int i = tid; i < BW; i += 256) cnt[i] = 0;
    __syncthreads();
    for (int e = ebase + tid; e < eend; e += 256)
        atomicAdd(&cnt[pairs[e] >> 17], 1);
    __syncthreads();

    int c0 = cnt[4 * tid], c1 = cnt[4 * tid + 1], c2 = cnt[4 * tid + 2], c3 = cnt[4 * tid + 3];
    aux[tid] = c0 + c1 + c2 + c3;
    __syncthreads();
    for (int off = 1; off < 256; off <<= 1) {
        int v = (tid >= off) ? aux[tid - off] : 0;
        __syncthreads();
        aux[tid] += v;
        __syncthreads();
    }
    int excl = tid ? aux[tid - 1] : 0;
    ex[4 * tid] = excl;
    ex[4 * tid + 1] = excl + c0;
    ex[4 * tid + 2] = excl + c0 + c1;
    ex[4 * tid + 3] = excl + c0 + c1 + c2;

    const int nodebase = b * BW + 4 * tid;
    if (nodebase + 0 < NN) rowend[nodebase + 0] = ebase + excl + c0;
    if (nodebase + 1 < NN) rowend[nodebase + 1] = ebase + excl + c0 + c1;
    if (nodebase + 2 < NN) rowend[nodebase + 2] = ebase + excl + c0 + c1 + c2;
    if (nodebase + 3 < NN) rowend[nodebase + 3] = ebase + excl + c0 + c1 + c2 + c3;
    __syncthreads();

    for (int e = ebase + tid; e < eend; e += 256) {
        unsigned pk = pairs[e];
        int dl = pk >> 17;
        int pos = ebase + atomicAdd(&ex[dl], 1);
        ssrc[pos] = (int)(pk & 0x1FFFFu);
    }
}

// ---------------------------------------------------------------------------
// Merged-graph fused SAGE layer (grid = 2*GEMMB; upper half = graph 1).
// fp8 gather tables (R5 structure — best measured). Layer1 self from fp32
// feats; layer2 self unpacked from the fp8 h1 table.
template<int KS, bool REDUCE>
__global__ __launch_bounds__(256) void sage_fused(
    const float* __restrict__ xf,
    const unsigned* __restrict__ x8a, const unsigned* __restrict__ x8b,
    const int* __restrict__ ss0, const int* __restrict__ ss1,
    const int* __restrict__ row0, const int* __restrict__ row1,
    const float* __restrict__ Wsa, const float* __restrict__ Wna,
    const float* __restrict__ Wsb, const float* __restrict__ Wnb,
    float* __restrict__ outRa, float* __restrict__ outRb,
    unsigned* __restrict__ outHa, unsigned* __restrict__ outHb) {
    __shared__ float xms[16][2 * KS + 4];
    __shared__ float part[4][128];

    const int tid = threadIdx.x;
    const int g = blockIdx.x >= GEMMB;
    const int n0 = (g ? blockIdx.x - GEMMB : blockIdx.x) * 16;
    const unsigned* x8 = g ? x8b : x8a;
    const int* ssrc = g ? ss1 : ss0;
    const int* rowend = g ? row1 : row0;
    const float* Ws = g ? Wsb : Wsa;
    const float* Wn = g ? Wnb : Wna;
    const uint4* xb4 = (const uint4*)x8;

    // ---- self staging ----
    {
        int node = tid / 16, c = tid % 16;
        if constexpr (KS == IND) {
            float4 v = ((const float4*)xf)[(size_t)(n0 + node) * 16 + c];
            *(float4*)&xms[node][c * 4] = v;
        } else {
            if (c < 8) {   // 8 uint4 per fp8 row of 128
                uint4 u = xb4[(size_t)(n0 + node) * 8 + c];
                float a[16];
#pragma unroll
                for (int j = 0; j < 16; j++) a[j] = 0.0f;
                bacc16(a, u);
                *(float4*)&xms[node][c * 16 + 0] = make_float4(a[0], a[1], a[2], a[3]);
                *(float4*)&xms[node][c * 16 + 4] = make_float4(a[4], a[5], a[6], a[7]);
                *(float4*)&xms[node][c * 16 + 8] = make_float4(a[8], a[9], a[10], a[11]);
                *(float4*)&xms[node][c * 16 + 12] = make_float4(a[12], a[13], a[14], a[15]);
            }
        }
    }

    // ---- neighbor mean aggregation (fp8 gather, fp32 acc) ----
    {
        const int nb = tid >> 4;
        const int n = n0 + nb;
        const int start = (n == 0) ? 0 : rowend[n - 1];
        const int end = rowend[n];
        float a[16];
#pragma unroll
        for (int j = 0; j < 16; j++) a[j] = 0.0f;

        if constexpr (KS == HID) {
            const int l = tid & 7;          // uint4 index (8/row)
            const int h = (tid >> 3) & 1;   // 2 chains
            int e = start + h;
            for (; e + 2 < end; e += 4) {
                int i0 = ssrc[e], i1 = ssrc[e + 2];
                uint4 v0 = xb4[(size_t)i0 * 8 + l];
                uint4 v1 = xb4[(size_t)i1 * 8 + l];
                bacc16(a, v0);
                bacc16(a, v1);
            }
            if (e < end) bacc16(a, xb4[(size_t)ssrc[e] * 8 + l]);
#pragma unroll
            for (int j = 0; j < 16; j++) a[j] += __shfl_xor(a[j], 8);
            if (h == 0) {
                float iv = 1.0f / fmaxf((float)(end - start), 1.0f);
                *(float4*)&xms[nb][KS + l * 16 + 0] = make_float4(a[0] * iv, a[1] * iv, a[2] * iv, a[3] * iv);
                *(float4*)&xms[nb][KS + l * 16 + 4] = make_float4(a[4] * iv, a[5] * iv, a[6] * iv, a[7] * iv);
                *(float4*)&xms[nb][KS + l * 16 + 8] = make_float4(a[8] * iv, a[9] * iv, a[10] * iv, a[11] * iv);
                *(float4*)&xms[nb][KS + l * 16 + 12] = make_float4(a[12] * iv, a[13] * iv, a[14] * iv, a[15] * iv);
            }
        } else {
            const int sub = tid & 15;
            const int l = sub & 3;          // uint4 index (4/row)
            const int h = sub >> 2;         // 4 chains
            int e = start + h;
            for (; e + 4 < end; e += 8) {
                int i0 = ssrc[e], i1 = ssrc[e + 4];
                uint4 v0 = xb4[(size_t)i0 * 4 + l];
                uint4 v1 = xb4[(size_t)i1 * 4 + l];
                bacc16(a, v0);
                bacc16(a, v1);
            }
            if (e < end) bacc16(a, xb4[(size_t)ssrc[e] * 4 + l]);
#pragma unroll
            for (int j = 0; j < 16; j++) a[j] += __shfl_xor(a[j], 4);
#pragma unroll
            for (int j = 0; j < 16; j++) a[j] += __shfl_xor(a[j], 8);
            if (h == 0) {
                float iv = 1.0f / fmaxf((float)(end - start), 1.0f);
                *(float4*)&xms[nb][KS + l * 16 + 0] = make_float4(a[0] * iv, a[1] * iv, a[2] * iv, a[3] * iv);
                *(float4*)&xms[nb][KS + l * 16 + 4] = make_float4(a[4] * iv, a[5] * iv, a[6] * iv, a[7] * iv);
                *(float4*)&xms[nb][KS + l * 16 + 8] = make_float4(a[8] * iv, a[9] * iv, a[10] * iv, a[11] * iv);
                *(float4*)&xms[nb][KS + l * 16 + 12] = make_float4(a[12] * iv, a[13] * iv, a[14] * iv, a[15] * iv);
            }
        }
    }
    __syncthreads();

    // ---- GEMM: out = relu([xs|ms] @ [Ws;Wn]) ----
    const int p = tid % 64;
    const int q = tid / 64;
    float a00 = 0, a01 = 0, a10 = 0, a11 = 0, a20 = 0, a21 = 0, a30 = 0, a31 = 0;

#pragma unroll
    for (int seg = 0; seg < 2; seg++) {
        const float* __restrict__ W = seg ? Wn : Ws;
        const int koff = seg * KS;
#pragma unroll 2
        for (int k = 0; k < KS; k += 4) {
            const float* Wk = W + (size_t)k * HID + 2 * p;
            float2 w0 = *(const float2*)(Wk);
            float2 w1 = *(const float2*)(Wk + HID);
            float2 w2 = *(const float2*)(Wk + 2 * HID);
            float2 w3 = *(const float2*)(Wk + 3 * HID);
            float4 v0 = *(const float4*)&xms[4 * q + 0][koff + k];
            float4 v1 = *(const float4*)&xms[4 * q + 1][koff + k];
            float4 v2 = *(const float4*)&xms[4 * q + 2][koff + k];
            float4 v3 = *(const float4*)&xms[4 * q + 3][koff + k];
            a00 += v0.x * w0.x + v0.y * w1.x + v0.z * w2.x + v0.w * w3.x;
            a01 += v0.x * w0.y + v0.y * w1.y + v0.z * w2.y + v0.w * w3.y;
            a10 += v1.x * w0.x + v1.y * w1.x + v1.z * w2.x + v1.w * w3.x;
            a11 += v1.x * w0.y + v1.y * w1.y + v1.z * w2.y + v1.w * w3.y;
            a20 += v2.x * w0.x + v2.y * w1.x + v2.z * w2.x + v2.w * w3.x;
            a21 += v2.x * w0.y + v2.y * w1.y + v2.z * w2.y + v2.w * w3.y;
            a30 += v3.x * w0.x + v3.y * w1.x + v3.z * w2.x + v3.w * w3.x;
            a31 += v3.x * w0.y + v3.y * w1.y + v3.z * w2.y + v3.w * w3.y;
        }
    }

    if constexpr (!REDUCE) {
        unsigned short* o8 = (unsigned short*)(g ? outHb : outHa);
        float r0, r1;
        r0 = fmaxf(a00, 0.f); r1 = fmaxf(a01, 0.f);
        o8[(size_t)(n0 + 4 * q + 0) * 64 + p] = (unsigned short)pk8<false>(r0, r1, 0u);
        r0 = fmaxf(a10, 0.f); r1 = fmaxf(a11, 0.f);
        o8[(size_t)(n0 + 4 * q + 1) * 64 + p] = (unsigned short)pk8<false>(r0, r1, 0u);
        r0 = fmaxf(a20, 0.f); r1 = fmaxf(a21, 0.f);
        o8[(size_t)(n0 + 4 * q + 2) * 64 + p] = (unsigned short)pk8<false>(r0, r1, 0u);
        r0 = fmaxf(a30, 0.f); r1 = fmaxf(a31, 0.f);
        o8[(size_t)(n0 + 4 * q + 3) * 64 + p] = (unsigned short)pk8<false>(r0, r1, 0u);
    } else {
        float* outR = g ? outRb : outRa;
        float s0 = fmaxf(a00, 0.f) + fmaxf(a10, 0.f) + fmaxf(a20, 0.f) + fmaxf(a30, 0.f);
        float s1 = fmaxf(a01, 0.f) + fmaxf(a11, 0.f) + fmaxf(a21, 0.f) + fmaxf(a31, 0.f);
        *(float2*)&part[q][2 * p] = make_float2(s0, s1);
        __syncthreads();
        if (tid < 128) {
            float s = part[0][tid] + part[1][tid] + part[2][tid] + part[3][tid];
            outR[(size_t)(g ? blockIdx.x - GEMMB : blockIdx.x) * 128 + tid] = s;
        }
    }
}

// ---------------------------------------------------------------------------
__global__ void reduce1_kernel(const float* __restrict__ p0, const float* __restrict__ p1,
                               float* __restrict__ p2) {
    const int bb = blockIdx.x;
    const int tid = threadIdx.x;
    const int g = tid >> 7;
    const int col = tid & 127;
    const float* p = g ? p1 : p0;
    const int per = GEMMB / RBLK;
    float s = 0.0f;
    for (int r = 0; r < per; r++) s += p[(size_t)(bb * per + r) * 128 + col];
    p2[(size_t)bb * 256 + tid] = s;
}

__global__ void final_kernel(const float* __restrict__ p2,
                             const float* __restrict__ Wlin1,
                             const float* __restrict__ Wlin2,
                             float* __restrict__ out) {
    __shared__ float rep[2][HID];
    __shared__ float sg[32];
    const int tid = threadIdx.x;
    float s = 0.0f;
    for (int r = 0; r < RBLK; r++) s += p2[r * 256 + tid];
    rep[tid >> 7][tid & 127] = s * (1.0f / (float)NN);
    __syncthreads();
    if (tid < 32) {
        const int g = tid / 16;
        const int c = tid % 16;
        const float* W = g ? Wlin2 : Wlin1;
        float a = 0.0f;
        for (int k = 0; k < HID; k++) a += rep[g][k] * W[k * NCLS + c];
        sg[tid] = 1.0f / (1.0f + expf(-a));
    }
    __syncthreads();
    if (tid < 16) out[tid] = 0.5f * (sg[tid] + sg[16 + tid]);
}

// ---------------------------------------------------------------------------
extern "C" void kernel_launch(void* const* d_in, const int* in_sizes, int n_in,
                              void* d_out, int out_size, void* d_ws, size_t ws_size,
                              hipStream_t stream) {
    const float* feats = (const float*)d_in[0];
    const int* srcp[2] = {(const int*)d_in[1], (const int*)d_in[3]};
    const int* dstp[2] = {(const int*)d_in[2], (const int*)d_in[4]};
    const float* Ws1[2] = {(const float*)d_in[5], (const float*)d_in[10]};
    const float* Wn1[2] = {(const float*)d_in[6], (const float*)d_in[11]};
    const float* Ws2[2] = {(const float*)d_in[7], (const float*)d_in[12]};
    const float* Wn2[2] = {(const float*)d_in[8], (const float*)d_in[13]};
    const float* Wlin[2] = {(const float*)d_in[9], (const float*)d_in[14]};

    // workspace (~52 MB). pairs buffers alias the h1 fp8 tables: pairs are
    // consumed by bucket_final BEFORE the sage kernels write h1. 16B-aligned.
    char* w = (char*)d_ws;
    unsigned* fb8 = (unsigned*)w;   w += (size_t)NN * IND;          // 6.4 MB
    unsigned* h18a = (unsigned*)w;  w += (size_t)NN * HID;          // 12.8 MB
    unsigned* h18b = (unsigned*)w;  w += (size_t)NN * HID;          // 12.8 MB
    float* part0 = (float*)w;       w += (size_t)GEMMB * 128 * 4;   // 3.2 MB
    float* part1 = (float*)w;       w += (size_t)GEMMB * 128 * 4;   // 3.2 MB
    float* p2 = (float*)w;          w += (size_t)RBLK * 256 * 4;
    int* ss0 = (int*)w;             w += (size_t)NE * 4;            // 6.4 MB
    int* ss1 = (int*)w;             w += (size_t)NE * 4;            // 6.4 MB
    int* row0 = (int*)w;            w += (size_t)NN * 4;
    int* row1 = (int*)w;            w += (size_t)NN * 4;
    int* bcnt = (int*)w;            w += 2 * BK * 4;
    int* bbase = (int*)w;           w += 2 * (BK + 1) * 4;
    int* bcur = (int*)w;            w += 2 * BK * 4;
    unsigned* pr0 = h18a;           // alias (dead before h1 writes)
    unsigned* pr1 = h18b;           // alias

    // feats -> fp8 table
    conv8_kernel<<<(NN * IND / 4 + 255) / 256, 256, 0, stream>>>(
        (const float4*)feats, fb8, NN * IND / 4);

    // bucketed CSR build, both graphs
    (void)hipMemsetAsync(bcnt, 0, 2 * BK * 4, stream);
    bucket_hist<<<2 * NBG, 256, 0, stream>>>(dstp[0], dstp[1], bcnt);
    bucket_scan<<<1, 64, 0, stream>>>(bcnt, bbase, bcur);
    bucket_place<<<2 * NBG, 256, 0, stream>>>(srcp[0], dstp[0], srcp[1], dstp[1],
                                              bcur, pr0, pr1);
    bucket_final<<<2 * BK, 256, 0, stream>>>(pr0, pr1, bbase, row0, row1, ss0, ss1);

    // layer 1, both graphs in one dispatch (12500 blocks)
    sage_fused<IND, false><<<2 * GEMMB, 256, 0, stream>>>(
        feats, fb8, fb8, ss0, ss1, row0, row1,
        Ws1[0], Wn1[0], Ws1[1], Wn1[1],
        nullptr, nullptr, h18a, h18b);

    // layer 2, both graphs in one dispatch
    sage_fused<HID, true><<<2 * GEMMB, 256, 0, stream>>>(
        nullptr, h18a, h18b, ss0, ss1, row0, row1,
        Ws2[0], Wn2[0], Ws2[1], Wn2[1],
        part0, part1, nullptr, nullptr);

    reduce1_kernel<<<RBLK, 256, 0, stream>>>(part0, part1, p2);
    final_kernel<<<1, 256, 0, stream>>>(p2, Wlin[0], Wlin[1], (float*)d_out);
}